// Round 4
// baseline (479.288 us; speedup 1.0000x reference)
//
#include <hip/hip_runtime.h>
#include <hip/hip_bf16.h>
#include <stdint.h>

typedef __attribute__((ext_vector_type(4))) float f32x4;
typedef __attribute__((ext_vector_type(8))) short short8;

__device__ __forceinline__ unsigned short f32_to_bf16_rne(float f) {
  union { float f; unsigned int u; } v; v.f = f;
  unsigned int u = v.u;
  unsigned int r = u + 0x7fffu + ((u >> 16) & 1u);
  return (unsigned short)(r >> 16);
}

#define GLOAD16(gp, lp)                                                 \
  __builtin_amdgcn_global_load_lds(                                     \
      (const __attribute__((address_space(1))) void*)(const void*)(gp), \
      (__attribute__((address_space(3))) void*)(void*)(lp), 16, 0, 0)

#define BAR() __builtin_amdgcn_s_barrier()
#define WAIT_LGKM0() asm volatile("s_waitcnt lgkmcnt(0)" ::: "memory")
#define WAIT_VM4() asm volatile("s_waitcnt vmcnt(4)" ::: "memory")
#define WAIT_VM0() asm volatile("s_waitcnt vmcnt(0)" ::: "memory")

// ---------------- converters / packers ----------------

__global__ __launch_bounds__(256) void cvt_f32_bf16(const float* __restrict__ in,
                                                    unsigned short* __restrict__ out,
                                                    int n4) {
  int i = blockIdx.x * 256 + threadIdx.x;
  int stride = gridDim.x * 256;
  for (; i < n4; i += stride) {
    float4 v = reinterpret_cast<const float4*>(in)[i];
    ushort4 o;
    o.x = f32_to_bf16_rne(v.x);
    o.y = f32_to_bf16_rne(v.y);
    o.z = f32_to_bf16_rne(v.z);
    o.w = f32_to_bf16_rne(v.w);
    reinterpret_cast<ushort4*>(out)[i] = o;
  }
}

// Bcat[16384][2048]: row R -> grp=R>>5, s=R&31; s<16: gate row grp*16+s,
// else up row grp*16+(s-16).
__global__ __launch_bounds__(256) void pack_gateup(const float* __restrict__ g,
                                                   const float* __restrict__ u,
                                                   unsigned short* __restrict__ out) {
  const int n = 16384 * 512;
  int idx = blockIdx.x * 256 + threadIdx.x;
  for (; idx < n; idx += gridDim.x * 256) {
    int R = idx >> 9, h4 = idx & 511;
    int grp = R >> 5, s = R & 31;
    const float* src = (s < 16 ? g : u) + (((size_t)(grp * 16 + (s & 15))) << 11) + (h4 << 2);
    float4 v = *reinterpret_cast<const float4*>(src);
    ushort4 o;
    o.x = f32_to_bf16_rne(v.x);
    o.y = f32_to_bf16_rne(v.y);
    o.z = f32_to_bf16_rne(v.z);
    o.w = f32_to_bf16_rne(v.w);
    *reinterpret_cast<ushort4*>(out + ((size_t)idx << 2)) = o;
  }
}

__global__ __launch_bounds__(256) void reduce_add(const float* __restrict__ a,
                                                  const float* __restrict__ b,
                                                  float* __restrict__ o, int n4) {
  int i = blockIdx.x * 256 + threadIdx.x;
  for (; i < n4; i += gridDim.x * 256) {
    float4 x = reinterpret_cast<const float4*>(a)[i];
    float4 y = reinterpret_cast<const float4*>(b)[i];
    float4 z;
    z.x = x.x + y.x; z.y = x.y + y.y; z.z = x.z + y.z; z.w = x.w + y.w;
    reinterpret_cast<float4*>(o)[i] = z;
  }
}

// ---------------- persistent 256x256x64 8-phase GEMM ----------------
// C = A(M x K) * B(N x K)^T, bf16 K-major. 8 waves, wave tile 128x64.
// Persistent: grid 256 blocks; block handles tpb consecutive tile ids
// (XCD-banded lin). Next tile's 12 prologue loads issue BEFORE the epilogue
// stores, hiding prologue latency; vmcnt(4) then restores the steady-state
// invariant (exactly the 4 newest loads in flight).

#define MFMA_Q(MH, NH)                                                        \
  do {                                                                        \
    _Pragma("unroll") for (int kh = 0; kh < 2; ++kh) {                        \
      _Pragma("unroll") for (int mi = 0; mi < 4; ++mi) {                      \
        _Pragma("unroll") for (int ni = 0; ni < 2; ++ni) {                    \
          acc[(MH)*4 + mi][(NH)*2 + ni] =                                     \
              __builtin_amdgcn_mfma_f32_16x16x32_bf16(                        \
                  a[mi][kh], b[(NH)*2 + ni][kh],                              \
                  acc[(MH)*4 + mi][(NH)*2 + ni], 0, 0, 0);                    \
        }                                                                     \
      }                                                                       \
    }                                                                         \
  } while (0)

#define STAGE(MAT, BUF, H, T)                                                 \
  do {                                                                        \
    const unsigned short* p0_ =                                               \
        MAT##base + (size_t)((H)*128 + r0) * ld##MAT + (size_t)(T)*64 + c0;   \
    const unsigned short* p1_ =                                               \
        MAT##base + (size_t)((H)*128 + r1) * ld##MAT + (size_t)(T)*64 + c1;   \
    GLOAD16(p0_, &s##MAT[BUF][H][off0 >> 1]);                                 \
    GLOAD16(p1_, &s##MAT[BUF][H][(off0 >> 1) + 512]);                         \
  } while (0)

#define LDA(dst, BUF, MI, KH)                                                 \
  {                                                                           \
    int lb_ = ((MI)*16 + frow) * 128 + (KH)*64 + kg * 16;                     \
    int ph_ = lb_ ^ ((frow & 7) << 4);                                        \
    dst = *reinterpret_cast<const short8*>(                                   \
        reinterpret_cast<const char*>(&sA[BUF][wr][0]) + ph_);                \
  }

#define LDB(dst, BUF, NI, KH)                                                 \
  {                                                                           \
    int lb_ = ((wc & 1) * 64 + (NI)*16 + frow) * 128 + (KH)*64 + kg * 16;     \
    int ph_ = lb_ ^ ((frow & 7) << 4);                                        \
    dst = *reinterpret_cast<const short8*>(                                   \
        reinterpret_cast<const char*>(&sB[BUF][wc >> 1][0]) + ph_);           \
  }

template <int EPI>
__global__ __launch_bounds__(512, 2) void gemm8p(
    const unsigned short* __restrict__ A, const unsigned short* __restrict__ B,
    void* __restrict__ Cout, int K, int ldA, int ldB, int Nout, size_t zstride,
    int nbm, int nbn, int tpb) {
  __shared__ unsigned short sA[2][2][128 * 64];
  __shared__ unsigned short sB[2][2][128 * 64];

  const int t = threadIdx.x;
  const int wv = t >> 6, ln = t & 63;
  const int wr = wv >> 2, wc = wv & 3;
  const int frow = ln & 15, kg = ln >> 4;

  // XCD-banded persistent tile assignment
  const int r = blockIdx.x;
  const int lin = (r & 7) * (gridDim.x >> 3) + (r >> 3);
  int g = lin * tpb;
  int bm = g % nbm;
  int rest = g / nbm;
  int bn = rest % nbn;
  int bz = rest / nbn;

  // staging precompute (tile-independent)
  const int off0 = wv * 2048 + ln * 16;
  const int off1 = off0 + 1024;
  const int s0 = off0 ^ (((off0 >> 7) & 7) << 4);
  const int s1 = off1 ^ (((off1 >> 7) & 7) << 4);
  const int r0 = s0 >> 7, c0 = (s0 & 127) >> 1;
  const int r1 = s1 >> 7, c1 = (s1 & 127) >> 1;

  const unsigned short* Abase = A + (size_t)bz * K + (size_t)(bm * 256) * ldA;
  const unsigned short* Bbase = B + (size_t)bz * K + (size_t)(bn * 256) * ldB;

  f32x4 acc[8][4] = {};
  short8 a[4][2], b[4][2];

  const int NT = K >> 6;

  // initial prologue: tile0 full (8 loads) + tile1 h0s (4 loads); vmcnt(4)
  // retires the oldest 8 = all of K-tile 0.
  STAGE(A, 0, 0, 0); STAGE(A, 0, 1, 0);
  STAGE(B, 0, 0, 0); STAGE(B, 0, 1, 0);
  STAGE(B, 1, 0, 1); STAGE(A, 1, 0, 1);
  WAIT_VM4();
  BAR();

  for (int ti = 0;; ++ti) {
    for (int tt = 0; tt < NT; ++tt) {
      const int buf = tt & 1, nbuf = buf ^ 1;
      // Phase 0
#pragma unroll
      for (int mi = 0; mi < 4; ++mi) { LDA(a[mi][0], buf, mi, 0); LDA(a[mi][1], buf, mi, 1); }
#pragma unroll
      for (int ni = 0; ni < 2; ++ni) { LDB(b[ni][0], buf, ni, 0); LDB(b[ni][1], buf, ni, 1); }
      if (tt + 1 < NT) STAGE(B, nbuf, 1, tt + 1);
      BAR(); WAIT_LGKM0();
      __builtin_amdgcn_s_setprio(1); MFMA_Q(0, 0); __builtin_amdgcn_s_setprio(0);
      BAR();
      // Phase 1
#pragma unroll
      for (int ni = 2; ni < 4; ++ni) { LDB(b[ni][0], buf, ni, 0); LDB(b[ni][1], buf, ni, 1); }
      if (tt + 1 < NT) STAGE(A, nbuf, 1, tt + 1);
      BAR(); WAIT_LGKM0();
      __builtin_amdgcn_s_setprio(1); MFMA_Q(0, 1); __builtin_amdgcn_s_setprio(0);
      BAR();
      // Phase 2
#pragma unroll
      for (int mi = 0; mi < 4; ++mi) { LDA(a[mi][0], buf, mi + 4, 0); LDA(a[mi][1], buf, mi + 4, 1); }
      if (tt + 2 < NT) STAGE(B, buf, 0, tt + 2);
      BAR(); WAIT_LGKM0();
      __builtin_amdgcn_s_setprio(1); MFMA_Q(1, 0); __builtin_amdgcn_s_setprio(0);
      BAR();
      // Phase 3
      if (tt + 2 < NT) STAGE(A, buf, 0, tt + 2);
      BAR(); WAIT_LGKM0();
      __builtin_amdgcn_s_setprio(1); MFMA_Q(1, 1); __builtin_amdgcn_s_setprio(0);
      if (tt < NT - 1) {
        if (tt + 2 < NT) { WAIT_VM4(); } else { WAIT_VM0(); }
      }
      BAR();
    }

    // epilogue coords for the tile just computed
    const int ebm = bm, ebn = bn, ebz = bz;
    const bool more = (ti + 1 < tpb);
    if (more) {
      // advance to next tile; issue its prologue BEFORE the epilogue stores
      ++g;
      bm = g % nbm;
      rest = g / nbm;
      bn = rest % nbn;
      bz = rest / nbn;
      Abase = A + (size_t)bz * K + (size_t)(bm * 256) * ldA;
      Bbase = B + (size_t)bz * K + (size_t)(bn * 256) * ldB;
      STAGE(A, 0, 0, 0); STAGE(A, 0, 1, 0);
      STAGE(B, 0, 0, 0); STAGE(B, 0, 1, 0);
      STAGE(B, 1, 0, 1); STAGE(A, 1, 0, 1);
    }

    if (EPI == 0) {
      float* C = reinterpret_cast<float*>(Cout) + (size_t)ebz * zstride;
      const int rb = ebm * 256 + wr * 128 + kg * 4;
      const int cb = ebn * 256 + wc * 64 + frow;
#pragma unroll
      for (int mi = 0; mi < 8; ++mi)
#pragma unroll
        for (int ni = 0; ni < 4; ++ni)
#pragma unroll
          for (int j = 0; j < 4; ++j)
            C[(size_t)(rb + mi * 16 + j) * Nout + (cb + ni * 16)] = acc[mi][ni][j];
    } else {
      unsigned short* Hm = reinterpret_cast<unsigned short*>(Cout);
      const int rb = ebm * 256 + wr * 128 + kg * 4;
      const int cb = ebn * 128 + wc * 32 + frow;
#pragma unroll
      for (int mi = 0; mi < 8; ++mi)
#pragma unroll
        for (int p = 0; p < 2; ++p)
#pragma unroll
          for (int j = 0; j < 4; ++j) {
            float gg = acc[mi][2 * p][j];
            float uu = acc[mi][2 * p + 1][j];
            float h = gg * uu * __builtin_amdgcn_rcpf(1.0f + __expf(-gg));
            Hm[(size_t)(rb + mi * 16 + j) * Nout + (cb + p * 16)] = f32_to_bf16_rne(h);
          }
    }

    if (!more) break;

    // stores (older) drain; exactly the 4 newest loads (tile1 h0s) stay in flight
    WAIT_VM4();
    BAR();
#pragma unroll
    for (int mi = 0; mi < 8; ++mi)
#pragma unroll
      for (int ni = 0; ni < 4; ++ni)
        acc[mi][ni] = (f32x4){0.f, 0.f, 0.f, 0.f};
  }
}

// ---------------- host ----------------

extern "C" void kernel_launch(void* const* d_in, const int* in_sizes, int n_in,
                              void* d_out, int out_size, void* d_ws, size_t ws_size,
                              hipStream_t stream) {
  const float* x      = (const float*)d_in[0];
  const float* gate_w = (const float*)d_in[1];
  const float* up_w   = (const float*)d_in[2];
  const float* down_w = (const float*)d_in[3];
  float* y = (float*)d_out;

  const int Mtok = 4096, H = 2048, I = 8192;

  unsigned short* x_bf = (unsigned short*)d_ws;
  unsigned short* Bcat = x_bf + (size_t)Mtok * H;
  unsigned short* d_bf = Bcat + (size_t)2 * I * H;
  unsigned short* h_bf = d_bf + (size_t)H * I;
  float* part = (float*)Bcat;  // reuses Bcat region after gemm1

  cvt_f32_bf16<<<2048, 256, 0, stream>>>(down_w, d_bf, (H * I) / 4);
  cvt_f32_bf16<<<2048, 256, 0, stream>>>(x, x_bf, (Mtok * H) / 4);
  pack_gateup<<<2048, 256, 0, stream>>>(gate_w, up_w, Bcat);

  // gemm1: persistent, 256 blocks x 4 tiles (bm fastest -> fixed bn per block)
  gemm8p<1><<<dim3(256), 512, 0, stream>>>(
      x_bf, Bcat, h_bf, H, H, H, I, 0, Mtok / 256, (2 * I) / 256, 4);

  // gemm2: split-K=2, 256 blocks, 1 tile each
  gemm8p<0><<<dim3(256), 512, 0, stream>>>(
      h_bf, d_bf, part, I / 2, I, I, H, (size_t)Mtok * H, Mtok / 256, H / 256, 1);

  reduce_add<<<2048, 256, 0, stream>>>(part, part + (size_t)Mtok * H, y,
                                       (Mtok * H) / 4);
}

// Round 5
// 457.648 us; speedup vs baseline: 1.0473x; 1.0473x over previous
//
#include <hip/hip_runtime.h>
#include <hip/hip_bf16.h>
#include <stdint.h>

typedef __attribute__((ext_vector_type(4))) float f32x4;
typedef __attribute__((ext_vector_type(8))) short short8;

__device__ __forceinline__ unsigned short f32_to_bf16_rne(float f) {
  union { float f; unsigned int u; } v; v.f = f;
  unsigned int u = v.u;
  unsigned int r = u + 0x7fffu + ((u >> 16) & 1u);
  return (unsigned short)(r >> 16);
}

#define GLOAD16(gp, lp)                                                 \
  __builtin_amdgcn_global_load_lds(                                     \
      (const __attribute__((address_space(1))) void*)(const void*)(gp), \
      (__attribute__((address_space(3))) void*)(void*)(lp), 16, 0, 0)

#define BAR() __builtin_amdgcn_s_barrier()
#define WAIT_LGKM0() asm volatile("s_waitcnt lgkmcnt(0)" ::: "memory")
#define WAIT_VM8() asm volatile("s_waitcnt vmcnt(8)" ::: "memory")
#define WAIT_VM0() asm volatile("s_waitcnt vmcnt(0)" ::: "memory")

// ---------------- converters / packers ----------------

__global__ __launch_bounds__(256) void cvt_f32_bf16(const float* __restrict__ in,
                                                    unsigned short* __restrict__ out,
                                                    int n4) {
  int i = blockIdx.x * 256 + threadIdx.x;
  int stride = gridDim.x * 256;
  for (; i < n4; i += stride) {
    float4 v = reinterpret_cast<const float4*>(in)[i];
    ushort4 o;
    o.x = f32_to_bf16_rne(v.x);
    o.y = f32_to_bf16_rne(v.y);
    o.z = f32_to_bf16_rne(v.z);
    o.w = f32_to_bf16_rne(v.w);
    reinterpret_cast<ushort4*>(out)[i] = o;
  }
}

// Bcat[16384][2048]: row R -> grp=R>>5, s=R&31; s<16: gate row grp*16+s,
// else up row grp*16+(s-16).
__global__ __launch_bounds__(256) void pack_gateup(const float* __restrict__ g,
                                                   const float* __restrict__ u,
                                                   unsigned short* __restrict__ out) {
  const int n = 16384 * 512;
  int idx = blockIdx.x * 256 + threadIdx.x;
  for (; idx < n; idx += gridDim.x * 256) {
    int R = idx >> 9, h4 = idx & 511;
    int grp = R >> 5, s = R & 31;
    const float* src = (s < 16 ? g : u) + (((size_t)(grp * 16 + (s & 15))) << 11) + (h4 << 2);
    float4 v = *reinterpret_cast<const float4*>(src);
    ushort4 o;
    o.x = f32_to_bf16_rne(v.x);
    o.y = f32_to_bf16_rne(v.y);
    o.z = f32_to_bf16_rne(v.z);
    o.w = f32_to_bf16_rne(v.w);
    *reinterpret_cast<ushort4*>(out + ((size_t)idx << 2)) = o;
  }
}

__global__ __launch_bounds__(256) void reduce_add(const float* __restrict__ a,
                                                  const float* __restrict__ b,
                                                  float* __restrict__ o, int n4) {
  int i = blockIdx.x * 256 + threadIdx.x;
  for (; i < n4; i += gridDim.x * 256) {
    float4 x = reinterpret_cast<const float4*>(a)[i];
    float4 y = reinterpret_cast<const float4*>(b)[i];
    float4 z;
    z.x = x.x + y.x; z.y = x.y + y.y; z.z = x.z + y.z; z.w = x.w + y.w;
    reinterpret_cast<float4*>(o)[i] = z;
  }
}

// ---------------- 256x256x64 8-phase GEMM, 2-tile-deep prefetch ----------
// C = A(M x K) * B(N x K)^T, bf16 K-major. 8 waves, wave tile 128x64.
// During tile t we stage ALL of tile t+2 (B halves at ph2, A halves at ph3 —
// the earliest race-free points), so the boundary vmcnt(8) only waits for
// loads issued 4-6 phases (~600-900 cy) earlier: absorbs HBM-miss latency.
// Steady state: 16 loads in flight, vmcnt(8) retires exactly tile t+1's 8.

#define MFMA_Q(MH, NH)                                                        \
  do {                                                                        \
    _Pragma("unroll") for (int kh = 0; kh < 2; ++kh) {                        \
      _Pragma("unroll") for (int mi = 0; mi < 4; ++mi) {                      \
        _Pragma("unroll") for (int ni = 0; ni < 2; ++ni) {                    \
          acc[(MH)*4 + mi][(NH)*2 + ni] =                                     \
              __builtin_amdgcn_mfma_f32_16x16x32_bf16(                        \
                  a[mi][kh], b[(NH)*2 + ni][kh],                              \
                  acc[(MH)*4 + mi][(NH)*2 + ni], 0, 0, 0);                    \
        }                                                                     \
      }                                                                       \
    }                                                                         \
  } while (0)

#define STAGE(MAT, BUF, H, T)                                                 \
  do {                                                                        \
    const unsigned short* p0_ =                                               \
        MAT##base + (size_t)((H)*128 + r0) * ld##MAT + (size_t)(T)*64 + c0;   \
    const unsigned short* p1_ =                                               \
        MAT##base + (size_t)((H)*128 + r1) * ld##MAT + (size_t)(T)*64 + c1;   \
    GLOAD16(p0_, &s##MAT[BUF][H][off0 >> 1]);                                 \
    GLOAD16(p1_, &s##MAT[BUF][H][(off0 >> 1) + 512]);                         \
  } while (0)

#define LDA(dst, BUF, MI, KH)                                                 \
  {                                                                           \
    int lb_ = ((MI)*16 + frow) * 128 + (KH)*64 + kg * 16;                     \
    int ph_ = lb_ ^ ((frow & 7) << 4);                                        \
    dst = *reinterpret_cast<const short8*>(                                   \
        reinterpret_cast<const char*>(&sA[BUF][wr][0]) + ph_);                \
  }

#define LDB(dst, BUF, NI, KH)                                                 \
  {                                                                           \
    int lb_ = ((wc & 1) * 64 + (NI)*16 + frow) * 128 + (KH)*64 + kg * 16;     \
    int ph_ = lb_ ^ ((frow & 7) << 4);                                        \
    dst = *reinterpret_cast<const short8*>(                                   \
        reinterpret_cast<const char*>(&sB[BUF][wc >> 1][0]) + ph_);           \
  }

template <int EPI>
__global__ __launch_bounds__(512, 2) void gemm8p(
    const unsigned short* __restrict__ A, const unsigned short* __restrict__ B,
    void* __restrict__ Cout, int K, int ldA, int ldB, int Nout, size_t zstride,
    int nbm, int nbn) {
  __shared__ unsigned short sA[2][2][128 * 64];
  __shared__ unsigned short sB[2][2][128 * 64];

  const int t = threadIdx.x;
  const int wv = t >> 6, ln = t & 63;
  const int wr = wv >> 2, wc = wv & 3;
  const int frow = ln & 15, kg = ln >> 4;

  // bijective XCD swizzle (gridDim.x % 8 == 0)
  const int r = blockIdx.x;
  const int swz = (r & 7) * (gridDim.x >> 3) + (r >> 3);
  const int bm = swz % nbm;
  const int rest = swz / nbm;
  const int bn = rest % nbn;
  const int bz = rest / nbn;

  A += (size_t)bz * K;
  B += (size_t)bz * K;

  const int off0 = wv * 2048 + ln * 16;
  const int off1 = off0 + 1024;
  const int s0 = off0 ^ (((off0 >> 7) & 7) << 4);
  const int s1 = off1 ^ (((off1 >> 7) & 7) << 4);
  const int r0 = s0 >> 7, c0 = (s0 & 127) >> 1;
  const int r1 = s1 >> 7, c1 = (s1 & 127) >> 1;

  const unsigned short* Abase = A + (size_t)(bm * 256) * ldA;
  const unsigned short* Bbase = B + (size_t)(bn * 256) * ldB;

  f32x4 acc[8][4] = {};
  short8 a[4][2], b[4][2];

  const int NT = K >> 6;  // NT >= 2

  // Prologue: tiles 0 and 1 fully staged (16 loads); vmcnt(8) retires tile 0.
  STAGE(A, 0, 0, 0); STAGE(A, 0, 1, 0);
  STAGE(B, 0, 0, 0); STAGE(B, 0, 1, 0);
  STAGE(A, 1, 0, 1); STAGE(A, 1, 1, 1);
  STAGE(B, 1, 0, 1); STAGE(B, 1, 1, 1);
  WAIT_VM8();
  BAR();

  for (int tt = 0; tt < NT; ++tt) {
    const int buf = tt & 1;
    // Phase 0: read a(m-lo) both halves, b(n-lo) both halves
#pragma unroll
    for (int mi = 0; mi < 4; ++mi) { LDA(a[mi][0], buf, mi, 0); LDA(a[mi][1], buf, mi, 1); }
#pragma unroll
    for (int ni = 0; ni < 2; ++ni) { LDB(b[ni][0], buf, ni, 0); LDB(b[ni][1], buf, ni, 1); }
    BAR(); WAIT_LGKM0();
    __builtin_amdgcn_s_setprio(1); MFMA_Q(0, 0); __builtin_amdgcn_s_setprio(0);
    BAR();
    // Phase 1: read b(n-hi)
#pragma unroll
    for (int ni = 2; ni < 4; ++ni) { LDB(b[ni][0], buf, ni, 0); LDB(b[ni][1], buf, ni, 1); }
    BAR(); WAIT_LGKM0();
    __builtin_amdgcn_s_setprio(1); MFMA_Q(0, 1); __builtin_amdgcn_s_setprio(0);
    BAR();
    // Phase 2: read a(m-hi); B[buf] reads done @ph1 -> stage B(t+2) both halves
#pragma unroll
    for (int mi = 0; mi < 4; ++mi) { LDA(a[mi][0], buf, mi + 4, 0); LDA(a[mi][1], buf, mi + 4, 1); }
    if (tt + 2 < NT) { STAGE(B, buf, 0, tt + 2); STAGE(B, buf, 1, tt + 2); }
    BAR(); WAIT_LGKM0();
    __builtin_amdgcn_s_setprio(1); MFMA_Q(1, 0); __builtin_amdgcn_s_setprio(0);
    BAR();
    // Phase 3: A[buf] reads done @ph2 -> stage A(t+2) both halves; boundary wait
    if (tt + 2 < NT) { STAGE(A, buf, 0, tt + 2); STAGE(A, buf, 1, tt + 2); }
    BAR(); WAIT_LGKM0();
    __builtin_amdgcn_s_setprio(1); MFMA_Q(1, 1); __builtin_amdgcn_s_setprio(0);
    if (tt < NT - 1) {
      if (tt + 2 < NT) { WAIT_VM8(); } else { WAIT_VM0(); }
    }
    BAR();
  }

  // ---------------- epilogue ----------------
  if (EPI == 0) {
    float* C = reinterpret_cast<float*>(Cout) + (size_t)bz * zstride;
    const int rb = bm * 256 + wr * 128 + kg * 4;
    const int cb = bn * 256 + wc * 64 + frow;
#pragma unroll
    for (int mi = 0; mi < 8; ++mi)
#pragma unroll
      for (int ni = 0; ni < 4; ++ni)
#pragma unroll
        for (int j = 0; j < 4; ++j)
          C[(size_t)(rb + mi * 16 + j) * Nout + (cb + ni * 16)] = acc[mi][ni][j];
  } else {
    unsigned short* Hm = reinterpret_cast<unsigned short*>(Cout);
    const int rb = bm * 256 + wr * 128 + kg * 4;
    const int cb = bn * 128 + wc * 32 + frow;
#pragma unroll
    for (int mi = 0; mi < 8; ++mi)
#pragma unroll
      for (int p = 0; p < 2; ++p)
#pragma unroll
        for (int j = 0; j < 4; ++j) {
          float gg = acc[mi][2 * p][j];
          float uu = acc[mi][2 * p + 1][j];
          float h = gg * uu * __builtin_amdgcn_rcpf(1.0f + __expf(-gg));
          Hm[(size_t)(rb + mi * 16 + j) * Nout + (cb + p * 16)] = f32_to_bf16_rne(h);
        }
  }
}

// ---------------- host ----------------

extern "C" void kernel_launch(void* const* d_in, const int* in_sizes, int n_in,
                              void* d_out, int out_size, void* d_ws, size_t ws_size,
                              hipStream_t stream) {
  const float* x      = (const float*)d_in[0];
  const float* gate_w = (const float*)d_in[1];
  const float* up_w   = (const float*)d_in[2];
  const float* down_w = (const float*)d_in[3];
  float* y = (float*)d_out;

  const int Mtok = 4096, H = 2048, I = 8192;

  unsigned short* x_bf = (unsigned short*)d_ws;
  unsigned short* Bcat = x_bf + (size_t)Mtok * H;
  unsigned short* d_bf = Bcat + (size_t)2 * I * H;
  unsigned short* h_bf = d_bf + (size_t)H * I;
  float* part = (float*)Bcat;  // reuses Bcat region after gemm1

  cvt_f32_bf16<<<2048, 256, 0, stream>>>(down_w, d_bf, (H * I) / 4);
  cvt_f32_bf16<<<2048, 256, 0, stream>>>(x, x_bf, (Mtok * H) / 4);
  pack_gateup<<<2048, 256, 0, stream>>>(gate_w, up_w, Bcat);

  // gemm1: (4096 x 2048) * (16384 x 2048)^T -> swiglu -> h_bf (4096 x 8192)
  gemm8p<1><<<dim3(1024), 512, 0, stream>>>(
      x_bf, Bcat, h_bf, H, H, H, I, 0, Mtok / 256, (2 * I) / 256);

  // gemm2: split-K=2: (4096 x 8192) * (2048 x 8192)^T -> partials
  gemm8p<0><<<dim3(256), 512, 0, stream>>>(
      h_bf, d_bf, part, I / 2, I, I, H, (size_t)Mtok * H, Mtok / 256, H / 256);

  reduce_add<<<2048, 256, 0, stream>>>(part, part + (size_t)Mtok * H, y,
                                       (Mtok * H) / 4);
}